// Round 7
// baseline (258.377 us; speedup 1.0000x reference)
//
#include <hip/hip_runtime.h>
#include <hip/hip_fp16.h>

// Problem constants (fixed instance)
#define IHc 128
#define IWc 256
#define OHc 256
#define OWc 512
#define Kc  4
#define Pc  4
#define Bc  4
#define Cc  128

constexpr int Nn  = IHc * IWc;        // 32768 input pixels
constexpr int Ee  = Nn * Kc * Pc;     // 524288 scatter entries
constexpr int Oo  = OHc * OWc;        // 131072 output pixels
constexpr int BC  = Bc * Cc;          // 512 planes
constexpr int NBLK = Oo / 256;        // 512 scan blocks

typedef float    f32x4 __attribute__((ext_vector_type(4)));
typedef unsigned u32x4 __attribute__((ext_vector_type(4)));
typedef int      i32x2 __attribute__((ext_vector_type(2)));

static __device__ __forceinline__ unsigned short h_bits(__half h) {
    unsigned short u; __builtin_memcpy(&u, &h, 2); return u;
}
static __device__ __forceinline__ float f_from_hbits(unsigned u) {
    __half h; unsigned short us = (unsigned short)(u & 0xffffu);
    __builtin_memcpy(&h, &us, 2); return __half2float(h);
}
static __device__ __forceinline__ float2 h2_to_f2(unsigned u) {
    __half2 h; __builtin_memcpy(&h, &u, 4); return __half22float2(h);
}

// ---------------- Phase 0: build CSR (output -> list of packed (n, w_fp16)) ----------------

__global__ void count_kernel(const i32x2* __restrict__ sm, int* __restrict__ counts) {
    int e = blockIdx.x * blockDim.x + threadIdx.x;
    if (e >= Ee) return;
    i32x2 xy = __builtin_nontemporal_load(&sm[e]);
    atomicAdd(&counts[xy.y * OWc + xy.x], 1);
}

__global__ void scan1(const int* __restrict__ counts, int* __restrict__ offsets,
                      int* __restrict__ bsum) {
    __shared__ int s[256];
    int tid = threadIdx.x;
    int i = blockIdx.x * 256 + tid;
    int v = counts[i];
    s[tid] = v;
    __syncthreads();
    for (int off = 1; off < 256; off <<= 1) {
        int t = (tid >= off) ? s[tid - off] : 0;
        __syncthreads();
        s[tid] += t;
        __syncthreads();
    }
    offsets[i] = s[tid] - v;              // block-local exclusive
    if (tid == 255) bsum[blockIdx.x] = s[tid];
}

__global__ void scan2(const int* __restrict__ bsum, int* __restrict__ bsumex) {
    __shared__ int s[NBLK];
    int tid = threadIdx.x;
    int v = bsum[tid];
    s[tid] = v;
    __syncthreads();
    for (int off = 1; off < NBLK; off <<= 1) {
        int t = (tid >= off) ? s[tid - off] : 0;
        __syncthreads();
        s[tid] += t;
        __syncthreads();
    }
    bsumex[tid] = s[tid] - v;             // exclusive block prefix
}

// pos via atomicSub on counts (counts still holds per-pixel totals after scan1)
__global__ void fill_kernel(const i32x2* __restrict__ sm, const float* __restrict__ iw,
                            const int* __restrict__ offsets, const int* __restrict__ bsumex,
                            int* __restrict__ counts, unsigned* __restrict__ entries) {
    int e = blockIdx.x * blockDim.x + threadIdx.x;
    if (e >= Ee) return;
    i32x2 xy = __builtin_nontemporal_load(&sm[e]);
    int o = xy.y * OWc + xy.x;
    float w = __builtin_nontemporal_load(&iw[e]) * 0.25f;   // interp_weights / KERNEL_SIZE
    int n = e >> 4;                                         // n = e / (K*P)
    unsigned ent = ((unsigned)n << 16) | (unsigned)h_bits(__float2half_rn(w));
    int pos = atomicSub(&counts[o], 1) - 1;                 // unique slot in [0, count)
    entries[offsets[o] + bsumex[o >> 8] + pos] = ent;
}

// ---------------- Phase T: transpose x (BC, Nn) f32 -> xT (Nn, BC) fp16 ----------------

#define TP 32   // planes per tile
#define TN 256  // n per tile

__global__ __launch_bounds__(256) void transpose_kernel(const float* __restrict__ x,
                                                        __half* __restrict__ xt) {
    __shared__ __half lds[TP][TN];
    int tid = threadIdx.x;
    int n0 = blockIdx.x * TN;
    int p0 = blockIdx.y * TP;
    #pragma unroll
    for (int i = 0; i < TP; ++i) {
        float v = __builtin_nontemporal_load(&x[(size_t)(p0 + i) * Nn + n0 + tid]);
        lds[i][tid] = __float2half_rn(v);
    }
    __syncthreads();
    alignas(16) __half tmp[TP];
    #pragma unroll
    for (int i = 0; i < TP; ++i) tmp[i] = lds[i][tid];
    f32x4* dst = (f32x4*)(xt + (size_t)(n0 + tid) * BC + p0);
    const f32x4* src = (const f32x4*)tmp;
    #pragma unroll
    for (int q = 0; q < TP / 8; ++q) dst[q] = src[q];
}

// ---------------- Phase 1: gather, plane-sliced ----------------
// Pass g covers planes [64g, 64g+64): the active xT slice is ONE 128 B line per
// row = 4 MB total -> fits per-XCD L2; reads become L2 hits, HBM sees writes only.
// Block = 256 px; wave w owns px [64w, 64w+64); lane l = (slot s=l>>3, qsub q=l&7).
// Slot s processes px 64w+8s+oi (oi=0..8): per j-batch, 8 slots read 8 entries'
// 128 B slices = 1 KB per wave instruction (same MLP as before). OOB j's load a
// pad entry (n=0, w=0) -> uniform control flow, plain x4 unroll.

#define PXB  256
#define SCAP 1536

#define ACCP(oi, raw, wf)                                          \
    {                                                              \
        float2 f0 = h2_to_f2((raw).x), f1 = h2_to_f2((raw).y);     \
        float2 f2 = h2_to_f2((raw).z), f3 = h2_to_f2((raw).w);     \
        acc[oi][0] += (wf) * f0.x;  acc[oi][1] += (wf) * f0.y;     \
        acc[oi][2] += (wf) * f1.x;  acc[oi][3] += (wf) * f1.y;     \
        acc[oi][4] += (wf) * f2.x;  acc[oi][5] += (wf) * f2.y;     \
        acc[oi][6] += (wf) * f3.x;  acc[oi][7] += (wf) * f3.y;     \
    }

__global__ __launch_bounds__(256) void gather6(const u32x4* __restrict__ xt4,
                                               const int* __restrict__ offsets,
                                               const int* __restrict__ bsumex,
                                               const unsigned* __restrict__ entries,
                                               float* __restrict__ out, int g) {
    __shared__ int soff[PXB + 1];
    __shared__ unsigned sent[SCAP];
    int tid = threadIdx.x;
    int o0 = blockIdx.x * PXB;

    for (int i = tid; i <= PXB; i += 256) {
        int go = o0 + i;
        soff[i] = (go < Oo) ? (offsets[go] + bsumex[go >> 8]) : Ee;
    }
    __syncthreads();
    int base = soff[0];
    int L = soff[PXB] - base;
    int Ll = (L < SCAP) ? L : SCAP;
    for (int j = tid; j < Ll; j += 256) sent[j] = entries[base + j];
    __syncthreads();

    int w = tid >> 6;     // wave -> px [64w, 64w+64)
    int l = tid & 63;
    int s = l >> 3;       // slot -> px 64w+8s+oi
    int q = l & 7;        // plane-sub -> planes [64g+8q, +8)
    const u32x4* __restrict__ xb = xt4 + (size_t)g * 8 + q;

    float acc[8][8];
    #pragma unroll
    for (int a = 0; a < 8; ++a)
        #pragma unroll
        for (int b = 0; b < 8; ++b) acc[a][b] = 0.f;

    int pxb = 64 * w + 8 * s;

#define GLOOP(GET)                                                          \
    _Pragma("unroll")                                                       \
    for (int oi = 0; oi < 8; ++oi) {                                        \
        int sA = soff[pxb + oi] - base;                                     \
        int cnt = soff[pxb + oi + 1] - base - sA;                           \
        for (int j = 0;; j += 4) {                                          \
            if (!__any(j < cnt)) break;                                     \
            unsigned E0, E1, E2, E3;                                        \
            { int jj=j+0; E0 = (jj<cnt) ? GET(sA+jj) : 0u; }                \
            { int jj=j+1; E1 = (jj<cnt) ? GET(sA+jj) : 0u; }                \
            { int jj=j+2; E2 = (jj<cnt) ? GET(sA+jj) : 0u; }                \
            { int jj=j+3; E3 = (jj<cnt) ? GET(sA+jj) : 0u; }                \
            u32x4 r0 = xb[(size_t)(E0 >> 16) * 64];                         \
            u32x4 r1 = xb[(size_t)(E1 >> 16) * 64];                         \
            u32x4 r2 = xb[(size_t)(E2 >> 16) * 64];                         \
            u32x4 r3 = xb[(size_t)(E3 >> 16) * 64];                         \
            float w0 = f_from_hbits(E0), w1 = f_from_hbits(E1);             \
            float w2 = f_from_hbits(E2), w3 = f_from_hbits(E3);             \
            ACCP(oi, r0, w0); ACCP(oi, r1, w1);                             \
            ACCP(oi, r2, w2); ACCP(oi, r3, w3);                             \
        }                                                                   \
    }

    if (L <= SCAP) {
#define GET_L(idx) (sent[idx])
        GLOOP(GET_L)
#undef GET_L
    } else {
#define GET_M(idx) ((idx) < SCAP ? sent[idx] : entries[base + (idx)])
        GLOOP(GET_M)
#undef GET_M
    }
#undef GLOOP

    // store: plane row p = 64g+8q+t gets px [o0+pxb, +8) — two same-wave f32x4
    // stores per row; slots' pieces tile 256 B contiguously per wave.
    float* ob = out + (size_t)(64 * g + 8 * q) * Oo + o0 + pxb;
    #pragma unroll
    for (int t = 0; t < 8; ++t) {
        f32x4 lo = { acc[0][t], acc[1][t], acc[2][t], acc[3][t] };
        f32x4 hi = { acc[4][t], acc[5][t], acc[6][t], acc[7][t] };
        *(f32x4*)(ob + (size_t)t * Oo)     = lo;
        *(f32x4*)(ob + (size_t)t * Oo + 4) = hi;
    }
}

// ---------------- Fallback (ws too small): correct but slow atomic scatter ----------------

__global__ void fallback_scatter(const float* __restrict__ x, const int* __restrict__ sm,
                                 const float* __restrict__ iw, float* __restrict__ out) {
    int e = blockIdx.x * blockDim.x + threadIdx.x;
    if (e >= Ee) return;
    int ox = sm[2 * e + 0];
    int oy = sm[2 * e + 1];
    int o = oy * OWc + ox;
    int n = e >> 4;
    float w = iw[e] * 0.25f;
    for (int p = 0; p < BC; ++p)
        atomicAdd(&out[(size_t)p * Oo + o], x[(size_t)p * Nn + n] * w);
}

// ---------------- launch ----------------

extern "C" void kernel_launch(void* const* d_in, const int* in_sizes, int n_in,
                              void* d_out, int out_size, void* d_ws, size_t ws_size,
                              hipStream_t stream) {
    const float* x  = (const float*)d_in[0];
    const int*   sm = (const int*)d_in[1];
    const float* iw = (const float*)d_in[2];
    float* out = (float*)d_out;

    // ws layout (bytes):
    //   offsets : (Oo+1)*4 = 524292  @ 0        (pad to 524800)
    //   counts  : Oo*4     = 524288  @ 524800
    //   bsum    : NBLK*4   = 2048    @ 1049088
    //   bsumex  : NBLK*4   = 2048    @ 1051136
    //   entries : Ee*4     = 2097152 @ 1053184
    //   xT      : Nn*BC*2  = 33554432@ 3150336  (16B aligned)
    constexpr size_t WS_NEED = 3150336 + (size_t)Nn * BC * 2;
    if (ws_size < WS_NEED) {
        (void)hipMemsetAsync(d_out, 0, (size_t)out_size * sizeof(float), stream);
        fallback_scatter<<<Ee / 256, 256, 0, stream>>>(x, sm, iw, out);
        return;
    }

    char* ws = (char*)d_ws;
    int*      offsets = (int*)(ws + 0);
    int*      counts  = (int*)(ws + 524800);
    int*      bsum    = (int*)(ws + 1049088);
    int*      bsumex  = (int*)(ws + 1051136);
    unsigned* entries = (unsigned*)(ws + 1053184);
    __half*   xt      = (__half*)(ws + 3150336);

    (void)hipMemsetAsync(counts, 0, Oo * sizeof(int), stream);

    count_kernel<<<Ee / 256, 256, 0, stream>>>((const i32x2*)sm, counts);
    scan1<<<NBLK, 256, 0, stream>>>(counts, offsets, bsum);
    scan2<<<1, NBLK, 0, stream>>>(bsum, bsumex);
    fill_kernel<<<Ee / 256, 256, 0, stream>>>((const i32x2*)sm, iw, offsets, bsumex,
                                              counts, entries);

    dim3 tgrid(Nn / TN, BC / TP);
    transpose_kernel<<<tgrid, 256, 0, stream>>>(x, xt);

    // 8 plane-sliced passes: separate dispatches guarantee temporal L2 slicing.
    for (int g = 0; g < 8; ++g)
        gather6<<<Oo / PXB, 256, 0, stream>>>((const u32x4*)xt, offsets, bsumex,
                                              entries, out, g);
}

// Round 8
// 245.163 us; speedup vs baseline: 1.0539x; 1.0539x over previous
//
#include <hip/hip_runtime.h>
#include <hip/hip_fp16.h>

// Problem constants (fixed instance)
#define IHc 128
#define IWc 256
#define OHc 256
#define OWc 512
#define Kc  4
#define Pc  4
#define Bc  4
#define Cc  128

constexpr int Nn  = IHc * IWc;        // 32768 input pixels
constexpr int Ee  = Nn * Kc * Pc;     // 524288 scatter entries
constexpr int Oo  = OHc * OWc;        // 131072 output pixels
constexpr int BC  = Bc * Cc;          // 512 planes
constexpr int NBLK = Oo / 256;        // 512 scan blocks

typedef float    f32x4 __attribute__((ext_vector_type(4)));
typedef unsigned u32x4 __attribute__((ext_vector_type(4)));
typedef int      i32x2 __attribute__((ext_vector_type(2)));

static __device__ __forceinline__ unsigned short h_bits(__half h) {
    unsigned short u; __builtin_memcpy(&u, &h, 2); return u;
}
static __device__ __forceinline__ float f_from_hbits(unsigned u) {
    __half h; unsigned short us = (unsigned short)(u & 0xffffu);
    __builtin_memcpy(&h, &us, 2); return __half2float(h);
}
static __device__ __forceinline__ float2 h2_to_f2(unsigned u) {
    __half2 h; __builtin_memcpy(&h, &u, 4); return __half22float2(h);
}

// ---------------- Phase 0: build CSR (output -> list of packed (n, w_fp16)) ----------------

__global__ void count_kernel(const i32x2* __restrict__ sm, int* __restrict__ counts) {
    int e = blockIdx.x * blockDim.x + threadIdx.x;
    if (e >= Ee) return;
    i32x2 xy = __builtin_nontemporal_load(&sm[e]);
    atomicAdd(&counts[xy.y * OWc + xy.x], 1);
}

__global__ void scan1(const int* __restrict__ counts, int* __restrict__ offsets,
                      int* __restrict__ bsum) {
    __shared__ int s[256];
    int tid = threadIdx.x;
    int i = blockIdx.x * 256 + tid;
    int v = counts[i];
    s[tid] = v;
    __syncthreads();
    for (int off = 1; off < 256; off <<= 1) {
        int t = (tid >= off) ? s[tid - off] : 0;
        __syncthreads();
        s[tid] += t;
        __syncthreads();
    }
    offsets[i] = s[tid] - v;              // block-local exclusive
    if (tid == 255) bsum[blockIdx.x] = s[tid];
}

__global__ void scan2(const int* __restrict__ bsum, int* __restrict__ bsumex) {
    __shared__ int s[NBLK];
    int tid = threadIdx.x;
    int v = bsum[tid];
    s[tid] = v;
    __syncthreads();
    for (int off = 1; off < NBLK; off <<= 1) {
        int t = (tid >= off) ? s[tid - off] : 0;
        __syncthreads();
        s[tid] += t;
        __syncthreads();
    }
    bsumex[tid] = s[tid] - v;             // exclusive block prefix
}

// pos via atomicSub on counts (counts still holds per-pixel totals after scan1)
__global__ void fill_kernel(const i32x2* __restrict__ sm, const float* __restrict__ iw,
                            const int* __restrict__ offsets, const int* __restrict__ bsumex,
                            int* __restrict__ counts, unsigned* __restrict__ entries) {
    int e = blockIdx.x * blockDim.x + threadIdx.x;
    if (e >= Ee) return;
    i32x2 xy = __builtin_nontemporal_load(&sm[e]);
    int o = xy.y * OWc + xy.x;
    float w = __builtin_nontemporal_load(&iw[e]) * 0.25f;   // interp_weights / KERNEL_SIZE
    int n = e >> 4;                                         // n = e / (K*P)
    unsigned ent = ((unsigned)n << 16) | (unsigned)h_bits(__float2half_rn(w));
    int pos = atomicSub(&counts[o], 1) - 1;                 // unique slot in [0, count)
    entries[offsets[o] + bsumex[o >> 8] + pos] = ent;
}

// ---------------- Phase T: transpose x (BC, Nn) f32 -> xT (Nn, BC) fp16 ----------------

#define TP 32   // planes per tile
#define TN 256  // n per tile

__global__ __launch_bounds__(256) void transpose_kernel(const float* __restrict__ x,
                                                        __half* __restrict__ xt) {
    __shared__ __half lds[TP][TN];
    int tid = threadIdx.x;
    int n0 = blockIdx.x * TN;
    int p0 = blockIdx.y * TP;
    #pragma unroll
    for (int i = 0; i < TP; ++i) {
        float v = __builtin_nontemporal_load(&x[(size_t)(p0 + i) * Nn + n0 + tid]);
        lds[i][tid] = __float2half_rn(v);
    }
    __syncthreads();
    alignas(16) __half tmp[TP];
    #pragma unroll
    for (int i = 0; i < TP; ++i) tmp[i] = lds[i][tid];
    f32x4* dst = (f32x4*)(xt + (size_t)(n0 + tid) * BC + p0);
    const f32x4* src = (const f32x4*)tmp;
    #pragma unroll
    for (int q = 0; q < TP / 8; ++q) dst[q] = src[q];
}

// ---------------- Phase 1: gather ----------------
// Block = 4 waves, TILE_O=32 consecutive output pixels x all 512 planes.
// Wave w owns pixels [8w,8w+8); lane l owns planes [8l,8l+8).
// One global_load_dwordx4 per entry covers all 512 planes (1 KB / wave-instr),
// entry loop unrolled x4 -> 4 outstanding loads per wave.
// Entries read DIRECTLY from global (each entry consumed once by one wave:
// LDS staging was pure overhead). tbuf shrunk to 16 KB via 4x 128-plane chunks.
// LDS 16.5 KB + VGPR<=64 -> 8 blocks/CU (32 waves) = 2x gather5's occupancy.

#define TILE_O 32

#define ACC8(oi, raw, wf)                                          \
    {                                                              \
        float2 f0 = h2_to_f2((raw).x), f1 = h2_to_f2((raw).y);     \
        float2 f2 = h2_to_f2((raw).z), f3 = h2_to_f2((raw).w);     \
        acc[oi][0] += (wf) * f0.x;  acc[oi][1] += (wf) * f0.y;     \
        acc[oi][2] += (wf) * f1.x;  acc[oi][3] += (wf) * f1.y;     \
        acc[oi][4] += (wf) * f2.x;  acc[oi][5] += (wf) * f2.y;     \
        acc[oi][6] += (wf) * f3.x;  acc[oi][7] += (wf) * f3.y;     \
    }

__global__ __launch_bounds__(256) void gather7(const u32x4* __restrict__ xt4,
                                               const int* __restrict__ offsets,
                                               const int* __restrict__ bsumex,
                                               const unsigned* __restrict__ entries,
                                               float* __restrict__ out) {
    __shared__ int soff[TILE_O + 1];
    __shared__ float tbuf[TILE_O][128];   // 16 KB transpose staging (128-plane chunk)

    int tid = threadIdx.x;
    int o0 = blockIdx.x * TILE_O;

    if (tid <= TILE_O) {
        int go = o0 + tid;
        soff[tid] = (go < Oo) ? (offsets[go] + bsumex[go >> 8]) : Ee;
    }
    __syncthreads();

    int w = tid >> 6;     // wave id -> pixels [8w, 8w+8)
    int l = tid & 63;     // lane    -> planes [8l, 8l+8)
    const u32x4* __restrict__ xrow = xt4 + l;

    float acc[8][8];
    #pragma unroll
    for (int a = 0; a < 8; ++a)
        #pragma unroll
        for (int b = 0; b < 8; ++b) acc[a][b] = 0.f;

    #pragma unroll
    for (int oi = 0; oi < 8; ++oi) {
        int s = soff[8 * w + oi];
        int e = soff[8 * w + oi + 1];
        int j = s;
        for (; j + 4 <= e; j += 4) {
            unsigned e0 = entries[j],     e1 = entries[j + 1];
            unsigned e2 = entries[j + 2], e3 = entries[j + 3];
            u32x4 r0 = xrow[(size_t)(e0 >> 16) * 64];
            u32x4 r1 = xrow[(size_t)(e1 >> 16) * 64];
            u32x4 r2 = xrow[(size_t)(e2 >> 16) * 64];
            u32x4 r3 = xrow[(size_t)(e3 >> 16) * 64];
            float w0 = f_from_hbits(e0), w1 = f_from_hbits(e1);
            float w2 = f_from_hbits(e2), w3 = f_from_hbits(e3);
            ACC8(oi, r0, w0); ACC8(oi, r1, w1);
            ACC8(oi, r2, w2); ACC8(oi, r3, w3);
        }
        for (; j < e; ++j) {
            unsigned e0 = entries[j];
            u32x4 r0 = xrow[(size_t)(e0 >> 16) * 64];
            float w0 = f_from_hbits(e0);
            ACC8(oi, r0, w0);
        }
    }

    // ---- epilogue: four 128-plane chunks; full-line stores per thread ----
    #pragma unroll
    for (int c = 0; c < 4; ++c) {
        __syncthreads();                       // tbuf free (main loop / prev chunk done)
        if ((l >> 4) == c) {                   // lanes holding planes [128c, 128c+128)
            int lp = (l & 15) * 8;             // plane_local base
            #pragma unroll
            for (int oi = 0; oi < 8; ++oi) {
                float* dst = &tbuf[8 * w + oi][lp];
                f32x4 lo = { acc[oi][0], acc[oi][1], acc[oi][2], acc[oi][3] };
                f32x4 hi = { acc[oi][4], acc[oi][5], acc[oi][6], acc[oi][7] };
                *(f32x4*)dst = lo;
                *(f32x4*)(dst + 4) = hi;
            }
        }
        __syncthreads();
        // thread tid<128 owns plane 128c+tid: read its 32-px column, write full line
        if (tid < 128) {
            float* orow = out + (size_t)(128 * c + tid) * Oo + o0;
            #pragma unroll
            for (int k = 0; k < 8; ++k) {
                f32x4 v = { tbuf[4 * k + 0][tid], tbuf[4 * k + 1][tid],
                            tbuf[4 * k + 2][tid], tbuf[4 * k + 3][tid] };
                *(f32x4*)(orow + 4 * k) = v;
            }
        }
    }
}

// ---------------- Fallback (ws too small): correct but slow atomic scatter ----------------

__global__ void fallback_scatter(const float* __restrict__ x, const int* __restrict__ sm,
                                 const float* __restrict__ iw, float* __restrict__ out) {
    int e = blockIdx.x * blockDim.x + threadIdx.x;
    if (e >= Ee) return;
    int ox = sm[2 * e + 0];
    int oy = sm[2 * e + 1];
    int o = oy * OWc + ox;
    int n = e >> 4;
    float w = iw[e] * 0.25f;
    for (int p = 0; p < BC; ++p)
        atomicAdd(&out[(size_t)p * Oo + o], x[(size_t)p * Nn + n] * w);
}

// ---------------- launch ----------------

extern "C" void kernel_launch(void* const* d_in, const int* in_sizes, int n_in,
                              void* d_out, int out_size, void* d_ws, size_t ws_size,
                              hipStream_t stream) {
    const float* x  = (const float*)d_in[0];
    const int*   sm = (const int*)d_in[1];
    const float* iw = (const float*)d_in[2];
    float* out = (float*)d_out;

    // ws layout (bytes):
    //   offsets : (Oo+1)*4 = 524292  @ 0        (pad to 524800)
    //   counts  : Oo*4     = 524288  @ 524800
    //   bsum    : NBLK*4   = 2048    @ 1049088
    //   bsumex  : NBLK*4   = 2048    @ 1051136
    //   entries : Ee*4     = 2097152 @ 1053184
    //   xT      : Nn*BC*2  = 33554432@ 3150336  (16B aligned)
    constexpr size_t WS_NEED = 3150336 + (size_t)Nn * BC * 2;
    if (ws_size < WS_NEED) {
        (void)hipMemsetAsync(d_out, 0, (size_t)out_size * sizeof(float), stream);
        fallback_scatter<<<Ee / 256, 256, 0, stream>>>(x, sm, iw, out);
        return;
    }

    char* ws = (char*)d_ws;
    int*      offsets = (int*)(ws + 0);
    int*      counts  = (int*)(ws + 524800);
    int*      bsum    = (int*)(ws + 1049088);
    int*      bsumex  = (int*)(ws + 1051136);
    unsigned* entries = (unsigned*)(ws + 1053184);
    __half*   xt      = (__half*)(ws + 3150336);

    (void)hipMemsetAsync(counts, 0, Oo * sizeof(int), stream);

    count_kernel<<<Ee / 256, 256, 0, stream>>>((const i32x2*)sm, counts);
    scan1<<<NBLK, 256, 0, stream>>>(counts, offsets, bsum);
    scan2<<<1, NBLK, 0, stream>>>(bsum, bsumex);
    fill_kernel<<<Ee / 256, 256, 0, stream>>>((const i32x2*)sm, iw, offsets, bsumex,
                                              counts, entries);

    dim3 tgrid(Nn / TN, BC / TP);
    transpose_kernel<<<tgrid, 256, 0, stream>>>(x, xt);

    gather7<<<Oo / TILE_O, 256, 0, stream>>>((const u32x4*)xt, offsets, bsumex, entries, out);
}

// Round 9
// 208.706 us; speedup vs baseline: 1.2380x; 1.1747x over previous
//
#include <hip/hip_runtime.h>
#include <hip/hip_fp16.h>

// Problem constants (fixed instance)
#define IHc 128
#define IWc 256
#define OHc 256
#define OWc 512
#define Kc  4
#define Pc  4
#define Bc  4
#define Cc  128

constexpr int Nn  = IHc * IWc;        // 32768 input pixels
constexpr int Ee  = Nn * Kc * Pc;     // 524288 scatter entries
constexpr int Oo  = OHc * OWc;        // 131072 output pixels
constexpr int BC  = Bc * Cc;          // 512 planes
constexpr int NBLK = Oo / 256;        // 512 scan blocks

typedef float    f32x4 __attribute__((ext_vector_type(4)));
typedef unsigned u32x4 __attribute__((ext_vector_type(4)));
typedef int      i32x2 __attribute__((ext_vector_type(2)));

static __device__ __forceinline__ unsigned short h_bits(__half h) {
    unsigned short u; __builtin_memcpy(&u, &h, 2); return u;
}
static __device__ __forceinline__ float f_from_hbits(unsigned u) {
    __half h; unsigned short us = (unsigned short)(u & 0xffffu);
    __builtin_memcpy(&h, &us, 2); return __half2float(h);
}
static __device__ __forceinline__ float2 h2_to_f2(unsigned u) {
    __half2 h; __builtin_memcpy(&h, &u, 4); return __half22float2(h);
}

// ---------------- Phase 0: build CSR (output -> list of packed (n, w_fp16)) ----------------

__global__ void count_kernel(const i32x2* __restrict__ sm, int* __restrict__ counts) {
    int e = blockIdx.x * blockDim.x + threadIdx.x;
    if (e >= Ee) return;
    i32x2 xy = __builtin_nontemporal_load(&sm[e]);
    atomicAdd(&counts[xy.y * OWc + xy.x], 1);
}

__global__ void scan1(const int* __restrict__ counts, int* __restrict__ offsets,
                      int* __restrict__ bsum) {
    __shared__ int s[256];
    int tid = threadIdx.x;
    int i = blockIdx.x * 256 + tid;
    int v = counts[i];
    s[tid] = v;
    __syncthreads();
    for (int off = 1; off < 256; off <<= 1) {
        int t = (tid >= off) ? s[tid - off] : 0;
        __syncthreads();
        s[tid] += t;
        __syncthreads();
    }
    offsets[i] = s[tid] - v;              // block-local exclusive
    if (tid == 255) bsum[blockIdx.x] = s[tid];
}

__global__ void scan2(const int* __restrict__ bsum, int* __restrict__ bsumex) {
    __shared__ int s[NBLK];
    int tid = threadIdx.x;
    int v = bsum[tid];
    s[tid] = v;
    __syncthreads();
    for (int off = 1; off < NBLK; off <<= 1) {
        int t = (tid >= off) ? s[tid - off] : 0;
        __syncthreads();
        s[tid] += t;
        __syncthreads();
    }
    bsumex[tid] = s[tid] - v;             // exclusive block prefix
}

// pos via atomicSub on counts (counts still holds per-pixel totals after scan1)
__global__ void fill_kernel(const i32x2* __restrict__ sm, const float* __restrict__ iw,
                            const int* __restrict__ offsets, const int* __restrict__ bsumex,
                            int* __restrict__ counts, unsigned* __restrict__ entries) {
    int e = blockIdx.x * blockDim.x + threadIdx.x;
    if (e >= Ee) return;
    i32x2 xy = __builtin_nontemporal_load(&sm[e]);
    int o = xy.y * OWc + xy.x;
    float w = __builtin_nontemporal_load(&iw[e]) * 0.25f;   // interp_weights / KERNEL_SIZE
    int n = e >> 4;                                         // n = e / (K*P)
    unsigned ent = ((unsigned)n << 16) | (unsigned)h_bits(__float2half_rn(w));
    int pos = atomicSub(&counts[o], 1) - 1;                 // unique slot in [0, count)
    entries[offsets[o] + bsumex[o >> 8] + pos] = ent;
}

// ---------------- Phase T: transpose x (BC, Nn) f32 -> xT (Nn, BC) fp16 ----------------

#define TP 32   // planes per tile
#define TN 256  // n per tile

__global__ __launch_bounds__(256) void transpose_kernel(const float* __restrict__ x,
                                                        __half* __restrict__ xt) {
    __shared__ __half lds[TP][TN];
    int tid = threadIdx.x;
    int n0 = blockIdx.x * TN;
    int p0 = blockIdx.y * TP;
    #pragma unroll
    for (int i = 0; i < TP; ++i) {
        float v = __builtin_nontemporal_load(&x[(size_t)(p0 + i) * Nn + n0 + tid]);
        lds[i][tid] = __float2half_rn(v);
    }
    __syncthreads();
    alignas(16) __half tmp[TP];
    #pragma unroll
    for (int i = 0; i < TP; ++i) tmp[i] = lds[i][tid];
    f32x4* dst = (f32x4*)(xt + (size_t)(n0 + tid) * BC + p0);
    const f32x4* src = (const f32x4*)tmp;
    #pragma unroll
    for (int q = 0; q < TP / 8; ++q) dst[q] = src[q];
}

// ---------------- Phase 1: gather ----------------
// Main loop identical to gather7 (proven: FETCH-clean 1 KB/instr loads).
// Epilogue redesigned for NONTEMPORAL FULL-LINE stores: per store instruction,
// each 8-lane group writes one complete 128 B output line -> nt streams to HBM
// with no RMW and no L2/L3 pollution, so xT (32 MB) stays L3-resident.
// tbuf pitch 129 + split-column layout (lo quad at col 4i, hi at 64+4i) makes
// both LDS staging and the column reads 2-way (free).

#define TILE_O 32
#define TPITCH 129

#define ACC8(oi, raw, wf)                                          \
    {                                                              \
        float2 f0 = h2_to_f2((raw).x), f1 = h2_to_f2((raw).y);     \
        float2 f2 = h2_to_f2((raw).z), f3 = h2_to_f2((raw).w);     \
        acc[oi][0] += (wf) * f0.x;  acc[oi][1] += (wf) * f0.y;     \
        acc[oi][2] += (wf) * f1.x;  acc[oi][3] += (wf) * f1.y;     \
        acc[oi][4] += (wf) * f2.x;  acc[oi][5] += (wf) * f2.y;     \
        acc[oi][6] += (wf) * f3.x;  acc[oi][7] += (wf) * f3.y;     \
    }

__global__ __launch_bounds__(256) void gather8(const u32x4* __restrict__ xt4,
                                               const int* __restrict__ offsets,
                                               const int* __restrict__ bsumex,
                                               const unsigned* __restrict__ entries,
                                               float* __restrict__ out) {
    __shared__ int soff[TILE_O + 1];
    __shared__ float tbuf[TILE_O][TPITCH];   // 16.5 KB transpose staging (128-plane chunk)

    int tid = threadIdx.x;
    int o0 = blockIdx.x * TILE_O;

    if (tid <= TILE_O) {
        int go = o0 + tid;
        soff[tid] = (go < Oo) ? (offsets[go] + bsumex[go >> 8]) : Ee;
    }
    __syncthreads();

    int w = tid >> 6;     // wave id -> pixels [8w, 8w+8)
    int l = tid & 63;     // lane    -> planes [8l, 8l+8)
    const u32x4* __restrict__ xrow = xt4 + l;

    float acc[8][8];
    #pragma unroll
    for (int a = 0; a < 8; ++a)
        #pragma unroll
        for (int b = 0; b < 8; ++b) acc[a][b] = 0.f;

    #pragma unroll
    for (int oi = 0; oi < 8; ++oi) {
        int s = soff[8 * w + oi];
        int e = soff[8 * w + oi + 1];
        int j = s;
        for (; j + 4 <= e; j += 4) {
            unsigned e0 = entries[j],     e1 = entries[j + 1];
            unsigned e2 = entries[j + 2], e3 = entries[j + 3];
            u32x4 r0 = xrow[(size_t)(e0 >> 16) * 64];
            u32x4 r1 = xrow[(size_t)(e1 >> 16) * 64];
            u32x4 r2 = xrow[(size_t)(e2 >> 16) * 64];
            u32x4 r3 = xrow[(size_t)(e3 >> 16) * 64];
            float w0 = f_from_hbits(e0), w1 = f_from_hbits(e1);
            float w2 = f_from_hbits(e2), w3 = f_from_hbits(e3);
            ACC8(oi, r0, w0); ACC8(oi, r1, w1);
            ACC8(oi, r2, w2); ACC8(oi, r3, w3);
        }
        for (; j < e; ++j) {
            unsigned e0 = entries[j];
            u32x4 r0 = xrow[(size_t)(e0 >> 16) * 64];
            float w0 = f_from_hbits(e0);
            ACC8(oi, r0, w0);
        }
    }

    // ---- epilogue: four 128-plane chunks; nt FULL-LINE stores ----
    // Staging (16 active lanes, i = l&15, planes [128c+8i, +8)):
    //   lo quad acc[oi][0..3] -> cols [4i, 4i+4); hi quad -> cols [64+4i, +4).
    // Store: lane l -> plane pl = 8k + (l>>3) (k = 4w+kk), chunk l&7 of the
    //   32-px row; 8-lane groups emit complete 128 B lines.
    #pragma unroll
    for (int c = 0; c < 4; ++c) {
        __syncthreads();                       // tbuf free (main loop / prev chunk done)
        if ((l >> 4) == c && w < 4) {          // lanes holding planes [128c, 128c+128)
            int i4 = (l & 15) * 4;
            #pragma unroll
            for (int oi = 0; oi < 8; ++oi) {
                float* row = tbuf[8 * w + oi];
                f32x4 lo = { acc[oi][0], acc[oi][1], acc[oi][2], acc[oi][3] };
                f32x4 hi = { acc[oi][4], acc[oi][5], acc[oi][6], acc[oi][7] };
                *(f32x4*)(row + i4)      = lo;
                *(f32x4*)(row + 64 + i4) = hi;
            }
        }
        __syncthreads();
        #pragma unroll
        for (int kk = 0; kk < 4; ++kk) {
            int k  = 4 * w + kk;               // plane-group 0..15 within chunk
            int q  = l >> 3;                   // plane-sub 0..7
            int pl = 8 * k + q;                // plane-local 0..127
            int col = (q < 4) ? (4 * k + q) : (60 + 4 * k + q);
            int px  = 4 * (l & 7);             // 16 B chunk of the 32-px row
            f32x4 v = { tbuf[px + 0][col], tbuf[px + 1][col],
                        tbuf[px + 2][col], tbuf[px + 3][col] };
            float* dst = out + (size_t)(128 * c + pl) * Oo + o0 + px;
            __builtin_nontemporal_store(v, (f32x4*)dst);
        }
    }
}

// ---------------- Fallback (ws too small): correct but slow atomic scatter ----------------

__global__ void fallback_scatter(const float* __restrict__ x, const int* __restrict__ sm,
                                 const float* __restrict__ iw, float* __restrict__ out) {
    int e = blockIdx.x * blockDim.x + threadIdx.x;
    if (e >= Ee) return;
    int ox = sm[2 * e + 0];
    int oy = sm[2 * e + 1];
    int o = oy * OWc + ox;
    int n = e >> 4;
    float w = iw[e] * 0.25f;
    for (int p = 0; p < BC; ++p)
        atomicAdd(&out[(size_t)p * Oo + o], x[(size_t)p * Nn + n] * w);
}

// ---------------- launch ----------------

extern "C" void kernel_launch(void* const* d_in, const int* in_sizes, int n_in,
                              void* d_out, int out_size, void* d_ws, size_t ws_size,
                              hipStream_t stream) {
    const float* x  = (const float*)d_in[0];
    const int*   sm = (const int*)d_in[1];
    const float* iw = (const float*)d_in[2];
    float* out = (float*)d_out;

    // ws layout (bytes):
    //   offsets : (Oo+1)*4 = 524292  @ 0        (pad to 524800)
    //   counts  : Oo*4     = 524288  @ 524800
    //   bsum    : NBLK*4   = 2048    @ 1049088
    //   bsumex  : NBLK*4   = 2048    @ 1051136
    //   entries : Ee*4     = 2097152 @ 1053184
    //   xT      : Nn*BC*2  = 33554432@ 3150336  (16B aligned)
    constexpr size_t WS_NEED = 3150336 + (size_t)Nn * BC * 2;
    if (ws_size < WS_NEED) {
        (void)hipMemsetAsync(d_out, 0, (size_t)out_size * sizeof(float), stream);
        fallback_scatter<<<Ee / 256, 256, 0, stream>>>(x, sm, iw, out);
        return;
    }

    char* ws = (char*)d_ws;
    int*      offsets = (int*)(ws + 0);
    int*      counts  = (int*)(ws + 524800);
    int*      bsum    = (int*)(ws + 1049088);
    int*      bsumex  = (int*)(ws + 1051136);
    unsigned* entries = (unsigned*)(ws + 1053184);
    __half*   xt      = (__half*)(ws + 3150336);

    (void)hipMemsetAsync(counts, 0, Oo * sizeof(int), stream);

    count_kernel<<<Ee / 256, 256, 0, stream>>>((const i32x2*)sm, counts);
    scan1<<<NBLK, 256, 0, stream>>>(counts, offsets, bsum);
    scan2<<<1, NBLK, 0, stream>>>(bsum, bsumex);
    fill_kernel<<<Ee / 256, 256, 0, stream>>>((const i32x2*)sm, iw, offsets, bsumex,
                                              counts, entries);

    dim3 tgrid(Nn / TN, BC / TP);
    transpose_kernel<<<tgrid, 256, 0, stream>>>(x, xt);

    gather8<<<Oo / TILE_O, 256, 0, stream>>>((const u32x4*)xt, offsets, bsumex, entries, out);
}